// Round 1
// baseline (132.063 us; speedup 1.0000x reference)
//
#include <hip/hip_runtime.h>
#include <cstdint>
#include <cstddef>

// ---- types ----------------------------------------------------------------
typedef __bf16 bf8 __attribute__((ext_vector_type(8)));
typedef float f32x4 __attribute__((ext_vector_type(4)));
typedef unsigned short us8 __attribute__((ext_vector_type(8)));
typedef unsigned short us4 __attribute__((ext_vector_type(4)));

__device__ __forceinline__ uint16_t f2b(float f) {
    uint32_t u = __builtin_bit_cast(uint32_t, f);
    u += 0x7FFFu + ((u >> 16) & 1u);          // round-to-nearest-even
    return (uint16_t)(u >> 16);
}
__device__ __forceinline__ float b2f(uint16_t h) {
    uint32_t u = ((uint32_t)h) << 16;
    return __builtin_bit_cast(float, u);
}

#define MFMA(a, b, c) __builtin_amdgcn_mfma_f32_16x16x32_bf16( \
    __builtin_bit_cast(bf8, (a)), __builtin_bit_cast(bf8, (b)), (c), 0, 0, 0)

// ---- prep: cast+transpose weights into ws ---------------------------------
// ws layout (uint16_t): w1t[64][32] @0, w2t[64][64] @2048, w3t[3072][64] @6144
__global__ void prep_weights(const float* __restrict__ W1,
                             const float* __restrict__ W2,
                             const float* __restrict__ W3,
                             uint16_t* __restrict__ wt) {
    int t = blockIdx.x * 256 + threadIdx.x;   // 0 .. 202751
    if (t < 2048) {                            // W1: [32][64], t = i*64+j
        int i = t >> 6, j = t & 63;
        wt[j * 32 + i] = f2b(W1[t]);
    } else if (t < 6144) {                     // W2: [64][64], t2 = k*64+j
        int t2 = t - 2048;
        int k = t2 >> 6, j = t2 & 63;
        wt[2048 + j * 64 + k] = f2b(W2[t2]);
    } else {                                   // W3: [64][3072], t3 = k*3072+j
        int t3 = t - 6144;
        int k = t3 / 3072, j = t3 - k * 3072;
        wt[6144 + j * 64 + k] = f2b(W3[t3]);
    }
}

// ---- fused main kernel ----------------------------------------------------
// block = 256 threads (4 waves), 64 edges per block.
// Phase B: tmp = feats@basis -> sh_tmp (bf16, m padded to 4, XOR-swizzled)
// Phase C: MLP via MFMA (M = out-ch, N = 16 edges per wave), LN+GELU in regs
// Phase D: rw = h@W3T via MFMA fused with per-fragment contraction over c
__global__ __launch_bounds__(256, 2) void pairconv_main(
    const float* __restrict__ edges, const float* __restrict__ feats,
    const float* __restrict__ basis,
    const float* __restrict__ b1, const float* __restrict__ g1, const float* __restrict__ be1,
    const float* __restrict__ b2, const float* __restrict__ g2, const float* __restrict__ be2,
    const uint16_t* __restrict__ wt, float* __restrict__ out) {

    // exactly 64 KiB static LDS
    __shared__ __align__(16) uint16_t sh_tmp[64 * 384];   // [e][cq^ (e&7)][...] 48 KiB
    __shared__ __align__(16) uint16_t sh_h[64 * 64];      // h (post-MLP), swizzled, 8 KiB
    __shared__ __align__(16) uint16_t sh_h1[4][16 * 64];  // per-wave h1, swizzled, 8 KiB

    const int tid = threadIdx.x;
    const int e0 = blockIdx.x * 64;
    const int lane = tid & 63, w = tid >> 6;
    const int n = lane & 15, q = lane >> 4;

    // ---------------- Phase B: tmp ------------------------------------------
    // item = (e in 0..63, i in 0..31); consecutive tid -> consecutive (e,i) with i inner
    #pragma unroll
    for (int it = 0; it < 8; ++it) {
        int idx = tid + it * 256;
        int e = idx >> 5, i = idx & 31;
        const float* fp = feats + ((size_t)(e0 + e) * 32 + i) * 3;
        float f0 = fp[0], f1 = fp[1], f2v = fp[2];
        const float* bp = basis + (size_t)(e0 + e) * 27;
        #pragma unroll
        for (int f = 0; f < 3; ++f) {
            int c = i * 3 + f;
            int cq = c >> 2, cl = c & 3;
            us4 pk;
            #pragma unroll
            for (int m = 0; m < 3; ++m) {
                float v = f0 * bp[f * 3 + m] + f1 * bp[9 + f * 3 + m] + f2v * bp[18 + f * 3 + m];
                pk[m] = f2b(v);
            }
            pk[3] = 0;
            *(us4*)&sh_tmp[e * 384 + ((cq ^ (e & 7)) << 4) + cl * 4] = pk;
        }
    }
    __syncthreads();

    // ---------------- Phase C: MLP (wave w -> edges eb..eb+15) --------------
    {
        const int eb = e0 + w * 16;
        // GEMM1 B-frag: x from global (fp32 -> bf16), K=32 exactly
        us8 bx;
        {
            const float* xp = edges + (size_t)(eb + n) * 32 + q * 8;
            #pragma unroll
            for (int j = 0; j < 8; ++j) bx[j] = f2b(xp[j]);
        }
        f32x4 acc[4];
        #pragma unroll
        for (int mt = 0; mt < 4; ++mt) {
            us8 a = *(const us8*)(wt + (mt * 16 + n) * 32 + q * 8);
            f32x4 z = {0.f, 0.f, 0.f, 0.f};
            acc[mt] = MFMA(a, bx, z);
        }
        // bias + LN + GELU (layer 1); lane holds j = mt*16 + q*4 + r of edge n
        float v[4][4];
        float s1 = 0.f, s2 = 0.f;
        #pragma unroll
        for (int mt = 0; mt < 4; ++mt) {
            f32x4 bb = *(const f32x4*)&b1[mt * 16 + q * 4];
            #pragma unroll
            for (int r = 0; r < 4; ++r) {
                float x = acc[mt][r] + bb[r];
                v[mt][r] = x; s1 += x; s2 += x * x;
            }
        }
        s1 += __shfl_xor(s1, 16, 64); s1 += __shfl_xor(s1, 32, 64);
        s2 += __shfl_xor(s2, 16, 64); s2 += __shfl_xor(s2, 32, 64);
        float mean = s1 * (1.f / 64.f);
        float var  = s2 * (1.f / 64.f) - mean * mean;
        float rs = rsqrtf(var + 1e-5f);
        #pragma unroll
        for (int mt = 0; mt < 4; ++mt) {
            f32x4 gg = *(const f32x4*)&g1[mt * 16 + q * 4];
            f32x4 be = *(const f32x4*)&be1[mt * 16 + q * 4];
            us4 pk;
            #pragma unroll
            for (int r = 0; r < 4; ++r) {
                float y = (v[mt][r] - mean) * rs * gg[r] + be[r];
                float g = 0.5f * y * (1.f + erff(y * 0.70710678118654752f));
                pk[r] = f2b(g);
            }
            // k = mt*16 + q*4 ; kq = k>>3, low half = (q&1)*4 ; swizzle by n&7
            int kq = mt * 2 + (q >> 1);
            *(us4*)&sh_h1[w][n * 64 + ((kq ^ (n & 7)) << 3) + (q & 1) * 4] = pk;
        }
    }
    __syncthreads();
    {
        // GEMM2: B-frag = h1g[edge=n][k], swizzled read (kq = q and 4+q)
        us8 bh0 = *(const us8*)&sh_h1[w][n * 64 + ((q ^ (n & 7)) << 3)];
        us8 bh1 = *(const us8*)&sh_h1[w][n * 64 + (((4 + q) ^ (n & 7)) << 3)];
        f32x4 acc[4];
        #pragma unroll
        for (int mt = 0; mt < 4; ++mt) {
            us8 a0 = *(const us8*)(wt + 2048 + (mt * 16 + n) * 64 + q * 8);
            us8 a1 = *(const us8*)(wt + 2048 + (mt * 16 + n) * 64 + 32 + q * 8);
            f32x4 z = {0.f, 0.f, 0.f, 0.f};
            acc[mt] = MFMA(a0, bh0, z);
            acc[mt] = MFMA(a1, bh1, acc[mt]);
        }
        float v[4][4]; float s1 = 0.f, s2 = 0.f;
        #pragma unroll
        for (int mt = 0; mt < 4; ++mt) {
            f32x4 bb = *(const f32x4*)&b2[mt * 16 + q * 4];
            #pragma unroll
            for (int r = 0; r < 4; ++r) {
                float x = acc[mt][r] + bb[r];
                v[mt][r] = x; s1 += x; s2 += x * x;
            }
        }
        s1 += __shfl_xor(s1, 16, 64); s1 += __shfl_xor(s1, 32, 64);
        s2 += __shfl_xor(s2, 16, 64); s2 += __shfl_xor(s2, 32, 64);
        float mean = s1 * (1.f / 64.f);
        float var  = s2 * (1.f / 64.f) - mean * mean;
        float rs = rsqrtf(var + 1e-5f);
        #pragma unroll
        for (int mt = 0; mt < 4; ++mt) {
            f32x4 gg = *(const f32x4*)&g2[mt * 16 + q * 4];
            f32x4 be = *(const f32x4*)&be2[mt * 16 + q * 4];
            us4 pk;
            #pragma unroll
            for (int r = 0; r < 4; ++r) {
                float y = (v[mt][r] - mean) * rs * gg[r] + be[r];
                float g = 0.5f * y * (1.f + erff(y * 0.70710678118654752f));
                pk[r] = f2b(g);
            }
            int e = w * 16 + n;                 // block-local edge
            int kq = mt * 2 + (q >> 1);
            *(us4*)&sh_h[e * 64 + ((kq ^ (e & 7)) << 3) + (q & 1) * 4] = pk;
        }
    }
    __syncthreads();

    // ---------------- Phase D: rw = h @ W3T fused with c-contraction --------
    {
        const uint16_t* w3t = wt + 6144;
        // B-frags: h for all 4 edge-subtiles, cached in regs (swizzled reads)
        us8 bh[4][2];
        #pragma unroll
        for (int nt = 0; nt < 4; ++nt) {
            int e = nt * 16 + n;
            bh[nt][0] = *(const us8*)&sh_h[e * 64 + ((q ^ (e & 7)) << 3)];
            bh[nt][1] = *(const us8*)&sh_h[e * 64 + (((4 + q) ^ (e & 7)) << 3)];
        }
        const int ob = w * 8;   // wave handles o in [ob, ob+8), split into 2 chunks of 4
        #pragma unroll 1
        for (int oc = 0; oc < 2; ++oc) {
            float p[4][4][3];   // [nt][o'][m]
            #pragma unroll
            for (int a = 0; a < 4; ++a)
                #pragma unroll
                for (int b = 0; b < 4; ++b)
                    #pragma unroll
                    for (int m = 0; m < 3; ++m) p[a][b][m] = 0.f;

            #pragma unroll 1
            for (int mt = 0; mt < 6; ++mt) {
                // tmp fragments: lane needs tmp[e=nt*16+n][c = mt*16+q*4 + r][m]
                float ftmp[4][4][3];
                #pragma unroll
                for (int nt = 0; nt < 4; ++nt) {
                    int e = nt * 16 + n;
                    int cq = mt * 4 + q;        // group of 4 c's
                    int base = e * 384 + ((cq ^ (e & 7)) << 4);
                    us8 t0 = *(const us8*)&sh_tmp[base];       // c, c+1
                    us8 t1 = *(const us8*)&sh_tmp[base + 8];   // c+2, c+3
                    #pragma unroll
                    for (int m = 0; m < 3; ++m) {
                        ftmp[nt][0][m] = b2f(t0[m]);
                        ftmp[nt][1][m] = b2f(t0[4 + m]);
                        ftmp[nt][2][m] = b2f(t1[m]);
                        ftmp[nt][3][m] = b2f(t1[4 + m]);
                    }
                }
                #pragma unroll
                for (int op = 0; op < 4; ++op) {
                    int o = ob + oc * 4 + op;
                    const uint16_t* ap = w3t + (size_t)(o * 96 + mt * 16 + n) * 64 + q * 8;
                    us8 a0 = *(const us8*)ap;
                    us8 a1 = *(const us8*)(ap + 32);
                    #pragma unroll
                    for (int nt = 0; nt < 4; ++nt) {
                        f32x4 z = {0.f, 0.f, 0.f, 0.f};
                        f32x4 acc = MFMA(a0, bh[nt][0], z);
                        acc = MFMA(a1, bh[nt][1], acc);
                        // acc[r] = rw[o*96 + mt*16 + q*4 + r][edge nt*16+n]
                        #pragma unroll
                        for (int r = 0; r < 4; ++r)
                            #pragma unroll
                            for (int m = 0; m < 3; ++m)
                                p[nt][op][m] += acc[r] * ftmp[nt][r][m];
                    }
                }
            }
            // reduce partial c-sums across q (xor 16, 32) and store
            #pragma unroll
            for (int nt = 0; nt < 4; ++nt) {
                #pragma unroll
                for (int op = 0; op < 4; ++op) {
                    int o = ob + oc * 4 + op;
                    float v0 = p[nt][op][0], v1 = p[nt][op][1], v2 = p[nt][op][2];
                    v0 += __shfl_xor(v0, 16, 64); v0 += __shfl_xor(v0, 32, 64);
                    v1 += __shfl_xor(v1, 16, 64); v1 += __shfl_xor(v1, 32, 64);
                    v2 += __shfl_xor(v2, 16, 64); v2 += __shfl_xor(v2, 32, 64);
                    float val = (q == 0) ? v0 : ((q == 1) ? v1 : v2);
                    if (q < 3)
                        out[(size_t)(e0 + nt * 16 + n) * 96 + o * 3 + q] = val;
                }
            }
        }
    }
}

// ---- launch ----------------------------------------------------------------
extern "C" void kernel_launch(void* const* d_in, const int* in_sizes, int n_in,
                              void* d_out, int out_size, void* d_ws, size_t ws_size,
                              hipStream_t stream) {
    const float* edges = (const float*)d_in[0];
    const float* feats = (const float*)d_in[1];
    const float* basis = (const float*)d_in[2];
    const float* W1  = (const float*)d_in[3];
    const float* b1  = (const float*)d_in[4];
    const float* g1  = (const float*)d_in[5];
    const float* be1 = (const float*)d_in[6];
    const float* W2  = (const float*)d_in[7];
    const float* b2  = (const float*)d_in[8];
    const float* g2  = (const float*)d_in[9];
    const float* be2 = (const float*)d_in[10];
    const float* W3  = (const float*)d_in[11];
    uint16_t* wt = (uint16_t*)d_ws;           // 202752 uint16 = 405504 B
    float* out = (float*)d_out;

    const int E = in_sizes[0] / 32;           // 32768
    hipLaunchKernelGGL(prep_weights, dim3(792), dim3(256), 0, stream, W1, W2, W3, wt);
    hipLaunchKernelGGL(pairconv_main, dim3(E / 64), dim3(256), 0, stream,
                       edges, feats, basis, b1, g1, be1, b2, g2, be2, wt, out);
}

// Round 2
// 130.363 us; speedup vs baseline: 1.0130x; 1.0130x over previous
//
#include <hip/hip_runtime.h>
#include <cstdint>
#include <cstddef>

// ---- types ----------------------------------------------------------------
typedef __bf16 bf8 __attribute__((ext_vector_type(8)));
typedef float f32x4 __attribute__((ext_vector_type(4)));
typedef float f32x4u __attribute__((ext_vector_type(4), aligned(4)));
typedef float f32x3u __attribute__((ext_vector_type(3), aligned(4)));
typedef unsigned short us8 __attribute__((ext_vector_type(8)));
typedef unsigned short us4 __attribute__((ext_vector_type(4)));

__device__ __forceinline__ uint16_t f2b(float f) {
    uint32_t u = __builtin_bit_cast(uint32_t, f);
    u += 0x7FFFu + ((u >> 16) & 1u);          // round-to-nearest-even
    return (uint16_t)(u >> 16);
}
__device__ __forceinline__ float b2f(uint16_t h) {
    uint32_t u = ((uint32_t)h) << 16;
    return __builtin_bit_cast(float, u);
}
// tanh-form GELU via hw exp+rcp: y*sigmoid(2*0.7978845608*(y+0.044715 y^3))
__device__ __forceinline__ float gelu_fast(float y) {
    float y3 = y * y * y;
    float z2 = 1.5957691216f * (y + 0.044715f * y3);
    float u = __expf(-z2);                     // v_exp_f32 path
    return y * __builtin_amdgcn_rcpf(1.0f + u);
}

#define MFMA(a, b, c) __builtin_amdgcn_mfma_f32_16x16x32_bf16( \
    __builtin_bit_cast(bf8, (a)), __builtin_bit_cast(bf8, (b)), (c), 0, 0, 0)

// ---- prep: cast+transpose weights into ws ---------------------------------
// ws layout (uint16_t): w1t[64][32] @0, w2t[64][64] @2048, w3t[3072][64] @6144
__global__ void prep_weights(const float* __restrict__ W1,
                             const float* __restrict__ W2,
                             const float* __restrict__ W3,
                             uint16_t* __restrict__ wt) {
    __shared__ float tile[32][33];
    int bx = blockIdx.x;
    if (bx < 192) {
        // W3[64][3072] -> w3t[3072][64], 32x32 LDS tile transpose
        int kb = (bx & 1) * 32;
        int jb = (bx >> 1) * 32;
        int tx = threadIdx.x & 31, ty = threadIdx.x >> 5;   // 32 x 8
        #pragma unroll
        for (int l = 0; l < 4; ++l)
            tile[ty + 8 * l][tx] = W3[(size_t)(kb + ty + 8 * l) * 3072 + jb + tx];
        __syncthreads();
        #pragma unroll
        for (int l = 0; l < 4; ++l) {
            int j = jb + ty + 8 * l;
            wt[6144 + (size_t)j * 64 + kb + tx] = f2b(tile[tx][ty + 8 * l]);
        }
    } else {
        int t = (bx - 192) * 256 + threadIdx.x;   // 0..6143
        if (t < 2048) {                            // W1: [32][64]
            int i = t >> 6, j = t & 63;
            wt[j * 32 + i] = f2b(W1[t]);
        } else {                                   // W2: [64][64]
            int t2 = t - 2048;
            int k = t2 >> 6, j = t2 & 63;
            wt[2048 + j * 64 + k] = f2b(W2[t2]);
        }
    }
}

// ---- fused main kernel ----------------------------------------------------
// block = 256 threads (4 waves), 64 edges per block. Single barrier.
__global__ __launch_bounds__(256, 2) void pairconv_main(
    const float* __restrict__ edges, const float* __restrict__ feats,
    const float* __restrict__ basis,
    const float* __restrict__ b1, const float* __restrict__ g1, const float* __restrict__ be1,
    const float* __restrict__ b2, const float* __restrict__ g2, const float* __restrict__ be2,
    const uint16_t* __restrict__ wt, float* __restrict__ out) {

    // 64 KiB static LDS
    // sh_tmp: per (e, chunk u=c>>1 in [0,48)): 8 uint16 (c0:m0m1m2,pad, c1:m0m1m2,pad)
    //         chunk placed at (u ^ (e&7)) -> 16B-granular bank swizzle
    __shared__ __align__(16) uint16_t sh_tmp[64 * 384];   // 48 KiB
    __shared__ __align__(16) uint16_t sh_h[64 * 64];      // 8 KiB
    __shared__ __align__(16) uint16_t sh_h1[4][16 * 64];  // 8 KiB (per-wave)

    const int tid = threadIdx.x;
    const int e0 = blockIdx.x * 64;
    const int lane = tid & 63, w = tid >> 6;
    const int n = lane & 15, q = lane >> 4;

    // ---- early-issue: edges for GEMM1 B-frag (HBM latency hidden by phase B)
    const int eb = e0 + w * 16;
    f32x4 ex0 = *(const f32x4*)(edges + (size_t)(eb + n) * 32 + q * 8);
    f32x4 ex1 = *(const f32x4*)(edges + (size_t)(eb + n) * 32 + q * 8 + 4);

    // ---------------- Phase B: tmp = feats@basis -> sh_tmp ------------------
    #pragma unroll
    for (int it = 0; it < 8; ++it) {
        int idx = tid + it * 256;
        int e = idx >> 5, i = idx & 31;
        f32x3u fv = *(const f32x3u*)(feats + ((size_t)(e0 + e) * 32 + i) * 3);
        const float* bpp = basis + (size_t)(e0 + e) * 27;
        float bp[27];
        #pragma unroll
        for (int v = 0; v < 6; ++v) {
            f32x4u t = *(const f32x4u*)(bpp + v * 4);
            bp[v * 4] = t[0]; bp[v * 4 + 1] = t[1]; bp[v * 4 + 2] = t[2]; bp[v * 4 + 3] = t[3];
        }
        bp[24] = bpp[24]; bp[25] = bpp[25]; bp[26] = bpp[26];
        int sw = e & 7;
        #pragma unroll
        for (int f = 0; f < 3; ++f) {
            int c = i * 3 + f;
            int u = c >> 1;
            us4 pk;
            #pragma unroll
            for (int m = 0; m < 3; ++m) {
                float v = fv[0] * bp[f * 3 + m] + fv[1] * bp[9 + f * 3 + m] + fv[2] * bp[18 + f * 3 + m];
                pk[m] = f2b(v);
            }
            pk[3] = 0;
            *(us4*)&sh_tmp[e * 384 + ((u ^ sw) << 3) + (c & 1) * 4] = pk;
        }
    }

    // ---------------- Phase C: MLP (wave w -> edges eb..eb+15) --------------
    {
        us8 bx;
        #pragma unroll
        for (int j = 0; j < 4; ++j) { bx[j] = f2b(ex0[j]); bx[4 + j] = f2b(ex1[j]); }
        f32x4 acc[4];
        #pragma unroll
        for (int mt = 0; mt < 4; ++mt) {
            us8 a = *(const us8*)(wt + (mt * 16 + n) * 32 + q * 8);
            f32x4 z = {0.f, 0.f, 0.f, 0.f};
            acc[mt] = MFMA(a, bx, z);
        }
        float v[4][4];
        float s1 = 0.f, s2 = 0.f;
        #pragma unroll
        for (int mt = 0; mt < 4; ++mt) {
            f32x4 bb = *(const f32x4*)&b1[mt * 16 + q * 4];
            #pragma unroll
            for (int r = 0; r < 4; ++r) {
                float x = acc[mt][r] + bb[r];
                v[mt][r] = x; s1 += x; s2 += x * x;
            }
        }
        s1 += __shfl_xor(s1, 16, 64); s1 += __shfl_xor(s1, 32, 64);
        s2 += __shfl_xor(s2, 16, 64); s2 += __shfl_xor(s2, 32, 64);
        float mean = s1 * (1.f / 64.f);
        float var  = s2 * (1.f / 64.f) - mean * mean;
        float rs = __builtin_amdgcn_rsqf(var + 1e-5f);
        #pragma unroll
        for (int mt = 0; mt < 4; ++mt) {
            f32x4 gg = *(const f32x4*)&g1[mt * 16 + q * 4];
            f32x4 be = *(const f32x4*)&be1[mt * 16 + q * 4];
            us4 pk;
            #pragma unroll
            for (int r = 0; r < 4; ++r) {
                float y = (v[mt][r] - mean) * rs * gg[r] + be[r];
                pk[r] = f2b(gelu_fast(y));
            }
            int kq = mt * 2 + (q >> 1);
            *(us4*)&sh_h1[w][n * 64 + ((kq ^ (n & 7)) << 3) + (q & 1) * 4] = pk;
        }
    }
    // NO barrier: sh_h1[w] is wave-private; DS ops from one wave are in-order.
    {
        us8 bh0 = *(const us8*)&sh_h1[w][n * 64 + ((q ^ (n & 7)) << 3)];
        us8 bh1 = *(const us8*)&sh_h1[w][n * 64 + (((4 + q) ^ (n & 7)) << 3)];
        f32x4 acc[4];
        #pragma unroll
        for (int mt = 0; mt < 4; ++mt) {
            us8 a0 = *(const us8*)(wt + 2048 + (mt * 16 + n) * 64 + q * 8);
            us8 a1 = *(const us8*)(wt + 2048 + (mt * 16 + n) * 64 + 32 + q * 8);
            f32x4 z = {0.f, 0.f, 0.f, 0.f};
            acc[mt] = MFMA(a0, bh0, z);
            acc[mt] = MFMA(a1, bh1, acc[mt]);
        }
        float v[4][4]; float s1 = 0.f, s2 = 0.f;
        #pragma unroll
        for (int mt = 0; mt < 4; ++mt) {
            f32x4 bb = *(const f32x4*)&b2[mt * 16 + q * 4];
            #pragma unroll
            for (int r = 0; r < 4; ++r) {
                float x = acc[mt][r] + bb[r];
                v[mt][r] = x; s1 += x; s2 += x * x;
            }
        }
        s1 += __shfl_xor(s1, 16, 64); s1 += __shfl_xor(s1, 32, 64);
        s2 += __shfl_xor(s2, 16, 64); s2 += __shfl_xor(s2, 32, 64);
        float mean = s1 * (1.f / 64.f);
        float var  = s2 * (1.f / 64.f) - mean * mean;
        float rs = __builtin_amdgcn_rsqf(var + 1e-5f);
        #pragma unroll
        for (int mt = 0; mt < 4; ++mt) {
            f32x4 gg = *(const f32x4*)&g2[mt * 16 + q * 4];
            f32x4 be = *(const f32x4*)&be2[mt * 16 + q * 4];
            us4 pk;
            #pragma unroll
            for (int r = 0; r < 4; ++r) {
                float y = (v[mt][r] - mean) * rs * gg[r] + be[r];
                pk[r] = f2b(gelu_fast(y));
            }
            int e = w * 16 + n;
            int kq = mt * 2 + (q >> 1);
            *(us4*)&sh_h[e * 64 + ((kq ^ (e & 7)) << 3) + (q & 1) * 4] = pk;
        }
    }
    __syncthreads();   // the ONLY barrier: covers sh_tmp + sh_h for phase D

    // ---------------- Phase D: rw = h @ W3T fused with c-contraction --------
    {
        const uint16_t* w3t = wt + 6144;
        us8 bh[4][2];
        #pragma unroll
        for (int nt = 0; nt < 4; ++nt) {
            int e = nt * 16 + n;
            bh[nt][0] = *(const us8*)&sh_h[e * 64 + ((q ^ (e & 7)) << 3)];
            bh[nt][1] = *(const us8*)&sh_h[e * 64 + (((4 + q) ^ (e & 7)) << 3)];
        }
        const int ob = w * 8;
        #pragma unroll 1
        for (int oc = 0; oc < 2; ++oc) {
            float p[4][4][3];
            #pragma unroll
            for (int a = 0; a < 4; ++a)
                #pragma unroll
                for (int b = 0; b < 4; ++b)
                    #pragma unroll
                    for (int m = 0; m < 3; ++m) p[a][b][m] = 0.f;

            #pragma unroll 1
            for (int mt = 0; mt < 6; ++mt) {
                float ftmp[4][4][3];
                #pragma unroll
                for (int nt = 0; nt < 4; ++nt) {
                    int e = nt * 16 + n;
                    int u0 = mt * 8 + q * 2;             // chunk index (c-pair)
                    int sw = e & 7;
                    us8 t0 = *(const us8*)&sh_tmp[e * 384 + ((u0 ^ sw) << 3)];
                    us8 t1 = *(const us8*)&sh_tmp[e * 384 + (((u0 + 1) ^ sw) << 3)];
                    #pragma unroll
                    for (int m = 0; m < 3; ++m) {
                        ftmp[nt][0][m] = b2f(t0[m]);
                        ftmp[nt][1][m] = b2f(t0[4 + m]);
                        ftmp[nt][2][m] = b2f(t1[m]);
                        ftmp[nt][3][m] = b2f(t1[4 + m]);
                    }
                }
                #pragma unroll
                for (int op = 0; op < 4; ++op) {
                    int o = ob + oc * 4 + op;
                    const uint16_t* ap = w3t + (size_t)(o * 96 + mt * 16 + n) * 64 + q * 8;
                    us8 a0 = *(const us8*)ap;
                    us8 a1 = *(const us8*)(ap + 32);
                    #pragma unroll
                    for (int nt = 0; nt < 4; ++nt) {
                        f32x4 z = {0.f, 0.f, 0.f, 0.f};
                        f32x4 acc = MFMA(a0, bh[nt][0], z);
                        acc = MFMA(a1, bh[nt][1], acc);
                        #pragma unroll
                        for (int r = 0; r < 4; ++r)
                            #pragma unroll
                            for (int m = 0; m < 3; ++m)
                                p[nt][op][m] += acc[r] * ftmp[nt][r][m];
                    }
                }
            }
            #pragma unroll
            for (int nt = 0; nt < 4; ++nt) {
                #pragma unroll
                for (int op = 0; op < 4; ++op) {
                    int o = ob + oc * 4 + op;
                    float v0 = p[nt][op][0], v1 = p[nt][op][1], v2 = p[nt][op][2];
                    v0 += __shfl_xor(v0, 16, 64); v0 += __shfl_xor(v0, 32, 64);
                    v1 += __shfl_xor(v1, 16, 64); v1 += __shfl_xor(v1, 32, 64);
                    v2 += __shfl_xor(v2, 16, 64); v2 += __shfl_xor(v2, 32, 64);
                    float val = (q == 0) ? v0 : ((q == 1) ? v1 : v2);
                    if (q < 3)
                        out[(size_t)(e0 + nt * 16 + n) * 96 + o * 3 + q] = val;
                }
            }
        }
    }
}

// ---- launch ----------------------------------------------------------------
extern "C" void kernel_launch(void* const* d_in, const int* in_sizes, int n_in,
                              void* d_out, int out_size, void* d_ws, size_t ws_size,
                              hipStream_t stream) {
    const float* edges = (const float*)d_in[0];
    const float* feats = (const float*)d_in[1];
    const float* basis = (const float*)d_in[2];
    const float* W1  = (const float*)d_in[3];
    const float* b1  = (const float*)d_in[4];
    const float* g1  = (const float*)d_in[5];
    const float* be1 = (const float*)d_in[6];
    const float* W2  = (const float*)d_in[7];
    const float* b2  = (const float*)d_in[8];
    const float* g2  = (const float*)d_in[9];
    const float* be2 = (const float*)d_in[10];
    const float* W3  = (const float*)d_in[11];
    uint16_t* wt = (uint16_t*)d_ws;           // 202752 uint16 = 405504 B
    float* out = (float*)d_out;

    const int E = in_sizes[0] / 32;           // 32768
    hipLaunchKernelGGL(prep_weights, dim3(216), dim3(256), 0, stream, W1, W2, W3, wt);
    hipLaunchKernelGGL(pairconv_main, dim3(E / 64), dim3(256), 0, stream,
                       edges, feats, basis, b1, g1, be1, b2, g2, be2, wt, out);
}